// Round 1
// baseline (80.637 us; speedup 1.0000x reference)
//
#include <hip/hip_runtime.h>
#include <hip/hip_bf16.h>

#define HIDDEN 256
#define SEQL   256
#define ALPHA  0.2f
#define L2E    1.4426950408889634f

typedef __attribute__((ext_vector_type(8))) short  short8;
typedef __attribute__((ext_vector_type(4))) float  f32x4;

__device__ __forceinline__ unsigned short f2bf(float f) {
    union { float f; unsigned int u; } v; v.f = f;
    unsigned int r = (v.u + 0x7FFFu + ((v.u >> 16) & 1u)) >> 16;   // RNE
    return (unsigned short)r;
}
__device__ __forceinline__ float bf2f(unsigned short h) {
    union { unsigned int u; float f; } v; v.u = ((unsigned int)h) << 16;
    return v.f;
}
__device__ __forceinline__ float lrelu(float x) { return fmaxf(x, ALPHA * x); }

// Swizzled 256x256 bf16 tile: row r (512B), 16B chunks permuted by chunk^(r&7).
// ushort index for element (r, c):
//   r*256 + (((c>>3) ^ (r&7)) << 3) + (c&7)
struct SMem {
    unsigned short xb[256 * 256];   // 128 KB: x (LN'ed) then hT (h transposed)
    unsigned short wt[128 * 40];    // 10 KB: Wt k-tile, row stride 40 ushorts (80B) vs bank conflicts
    float s1[256], s2[256];
    float mrow[256], linv[256];
    float a1s[256], a2s[256];
    int   seq[256];
    float s2max;
};

__global__ __launch_bounds__(512, 2)
void gat_fused(const int* __restrict__ item_seq, const float* __restrict__ emb,
               const float* __restrict__ pos, const float* __restrict__ W,
               const float* __restrict__ a1, const float* __restrict__ a2,
               const float* __restrict__ gamma, const float* __restrict__ beta,
               float* __restrict__ out)
{
    __shared__ SMem sm;
    const int b    = blockIdx.x;
    const int tid  = threadIdx.x;
    const int lane = tid & 63;
    const int wv   = tid >> 6;          // wave 0..7
    const int g    = lane >> 4;         // 16-lane group 0..3
    const int li   = lane & 15;

    // ---------------- Phase 0: seq / a1 / a2 into LDS ----------------
    if (tid < 256) {
        sm.seq[tid] = item_seq[(size_t)b * SEQL + tid];
        sm.a1s[tid] = a1[tid];
        sm.a2s[tid] = a2[tid];
    }
    __syncthreads();

    // ---------------- Phase A: gather + LayerNorm -> xb (bf16, swizzled) ----
    // wave handles rows r = it*8 + wv; 64 lanes cover the 256 cols as float4
    {
        float4 g4 = *(const float4*)(gamma + 4 * lane);
        float4 b4 = *(const float4*)(beta  + 4 * lane);
        for (int it = 0; it < 32; ++it) {
            int r  = it * 8 + wv;
            int iw = sm.seq[r];
            float4 e4 = *(const float4*)(emb + (size_t)iw * HIDDEN + 4 * lane);
            float4 p4 = *(const float4*)(pos + (size_t)r  * HIDDEN + 4 * lane);
            float x0 = e4.x + p4.x, x1 = e4.y + p4.y, x2 = e4.z + p4.z, x3 = e4.w + p4.w;
            float s = x0 + x1 + x2 + x3;
            float q = x0*x0 + x1*x1 + x2*x2 + x3*x3;
            #pragma unroll
            for (int off = 32; off; off >>= 1) {
                s += __shfl_xor(s, off);
                q += __shfl_xor(q, off);
            }
            float mu  = s * (1.0f / 256.0f);
            float var = q * (1.0f / 256.0f) - mu * mu;
            float rs  = rsqrtf(var + 1e-12f);
            x0 = (x0 - mu) * rs * g4.x + b4.x;
            x1 = (x1 - mu) * rs * g4.y + b4.y;
            x2 = (x2 - mu) * rs * g4.z + b4.z;
            x3 = (x3 - mu) * rs * g4.w + b4.w;
            ushort4 o;
            o.x = f2bf(x0); o.y = f2bf(x1); o.z = f2bf(x2); o.w = f2bf(x3);
            int chunk = lane >> 1;                 // c4 = lane -> chunk = lane>>1
            int sub   = (lane & 1) * 4;
            *(ushort4*)&sm.xb[r * 256 + (((chunk ^ (r & 7))) << 3) + sub] = o;
        }
    }
    __syncthreads();

    // ---------------- Phase C: h = x @ W (MFMA), two N-halves ----------------
    const int ig = wv >> 1;   // m-group: rows ig*64
    const int ng = wv & 1;    // n-group within half: cols ng*64
    unsigned int stash[32];   // half-0 results as packed bf16
    f32x4 acc[4][4];

    for (int half = 0; half < 2; ++half) {
        #pragma unroll
        for (int mt = 0; mt < 4; ++mt)
            #pragma unroll
            for (int nt = 0; nt < 4; ++nt)
                acc[mt][nt] = (f32x4){0.f, 0.f, 0.f, 0.f};

        for (int ks = 0; ks < 8; ++ks) {
            __syncthreads();   // protect previous iter's wt reads
            {   // stage Wt tile: thread (kk=tid>>7, c=tid&127) loads 8 k's, one b128 write
                int kk = tid >> 7, c = tid & 127;
                const float* wp = W + (size_t)(ks * 32 + kk * 8) * HIDDEN + half * 128 + c;
                unsigned int pk[4];
                #pragma unroll
                for (int q2 = 0; q2 < 4; ++q2) {
                    unsigned short w0 = f2bf(wp[(2*q2  ) * HIDDEN]);
                    unsigned short w1 = f2bf(wp[(2*q2+1) * HIDDEN]);
                    pk[q2] = (unsigned int)w0 | ((unsigned int)w1 << 16);
                }
                int4 v; v.x = pk[0]; v.y = pk[1]; v.z = pk[2]; v.w = pk[3];
                *(int4*)&sm.wt[c * 40 + kk * 8] = v;
            }
            __syncthreads();

            short8 bfr[4];
            #pragma unroll
            for (int nt = 0; nt < 4; ++nt) {
                int c = ng * 64 + nt * 16 + li;
                bfr[nt] = *(const short8*)&sm.wt[c * 40 + g * 8];
            }
            #pragma unroll
            for (int mt = 0; mt < 4; ++mt) {
                int r  = ig * 64 + mt * 16 + li;
                int kc = ks * 4 + g;
                short8 af = *(const short8*)&sm.xb[r * 256 + ((kc ^ (r & 7)) << 3)];
                #pragma unroll
                for (int nt = 0; nt < 4; ++nt)
                    acc[mt][nt] = __builtin_amdgcn_mfma_f32_16x16x32_bf16(
                        af, bfr[nt], acc[mt][nt], 0, 0, 0);
            }
        }
        if (half == 0) {
            #pragma unroll
            for (int mt = 0; mt < 4; ++mt)
                #pragma unroll
                for (int nt = 0; nt < 4; ++nt) {
                    int t = (mt * 4 + nt) * 2;
                    stash[t]   = (unsigned)f2bf(acc[mt][nt][0]) | ((unsigned)f2bf(acc[mt][nt][1]) << 16);
                    stash[t+1] = (unsigned)f2bf(acc[mt][nt][2]) | ((unsigned)f2bf(acc[mt][nt][3]) << 16);
                }
        }
    }
    __syncthreads();   // all xb (=x) reads complete before overwrite with hT

    // ---------------- write hT into xb (swizzled) ----------------
    #pragma unroll
    for (int half = 0; half < 2; ++half)
        #pragma unroll
        for (int mt = 0; mt < 4; ++mt)
            #pragma unroll
            for (int nt = 0; nt < 4; ++nt) {
                int c  = half * 128 + ng * 64 + nt * 16 + li;
                int i0 = ig * 64 + mt * 16 + 4 * g;
                unsigned int lo, hi;
                if (half == 0) {
                    int t = (mt * 4 + nt) * 2;
                    lo = stash[t]; hi = stash[t + 1];
                } else {
                    lo = (unsigned)f2bf(acc[mt][nt][0]) | ((unsigned)f2bf(acc[mt][nt][1]) << 16);
                    hi = (unsigned)f2bf(acc[mt][nt][2]) | ((unsigned)f2bf(acc[mt][nt][3]) << 16);
                }
                uint2 v; v.x = lo; v.y = hi;
                *(uint2*)&sm.xb[c * 256 + (((i0 >> 3) ^ (c & 7)) << 3) + (i0 & 7)] = v;
            }
    __syncthreads();

    // ---------------- Phase D: s1 = h@a1, s2 = h@a2 (from hT) ----------------
    {
        int arr  = wv >> 2;               // 0 -> s1, 1 -> s2
        int i    = (wv & 3) * 64 + lane;
        const float* av = arr ? sm.a2s : sm.a1s;
        int ich = i >> 3, isub = i & 7;
        float accd = 0.f;
        for (int c = 0; c < 256; ++c) {
            unsigned short h = sm.xb[c * 256 + ((ich ^ (c & 7)) << 3) + isub];
            accd += bf2f(h) * av[c];
        }
        if (arr) sm.s2[i] = accd; else sm.s1[i] = accd;
    }
    __syncthreads();

    // ---------------- Phase E: s2max, m_i, 1/l_i ----------------
    if (wv == 0) {
        float m0 = fmaxf(fmaxf(sm.s2[lane], sm.s2[lane + 64]),
                         fmaxf(sm.s2[lane + 128], sm.s2[lane + 192]));
        #pragma unroll
        for (int off = 32; off; off >>= 1) m0 = fmaxf(m0, __shfl_xor(m0, off));
        if (lane == 0) sm.s2max = m0;
    }
    __syncthreads();
    {
        int i  = (wv << 5) + (lane & 31);
        int jh = lane >> 5;
        float s1v = sm.s1[i];
        float mi  = lrelu(s1v + sm.s2max);
        float sum = 0.f;
        for (int j = jh * 128; j < jh * 128 + 128; ++j) {
            float e = lrelu(s1v + sm.s2[j]);
            sum += __builtin_amdgcn_exp2f((e - mi) * L2E);
        }
        sum += __shfl_xor(sum, 32);
        if (jh == 0) { sm.mrow[i] = mi; sm.linv[i] = 1.0f / sum; }
    }
    __syncthreads();

    // ---------------- Phase F: out = P @ h (MFMA), P built in-register ------
    {
        const int ig2 = wv >> 1;    // i-block: ig2*64
        const int ng2 = wv & 1;     // n-half:  ng2*128
        f32x4 oacc[4][8];
        #pragma unroll
        for (int mt = 0; mt < 4; ++mt)
            #pragma unroll
            for (int nt = 0; nt < 8; ++nt)
                oacc[mt][nt] = (f32x4){0.f, 0.f, 0.f, 0.f};

        float s1v[4], mv[4], lv[4];
        #pragma unroll
        for (int mt = 0; mt < 4; ++mt) {
            int i = ig2 * 64 + mt * 16 + li;
            s1v[mt] = sm.s1[i]; mv[mt] = sm.mrow[i]; lv[mt] = sm.linv[i];
        }

        for (int js = 0; js < 8; ++js) {
            float s2l[8];
            #pragma unroll
            for (int jj = 0; jj < 8; ++jj) s2l[jj] = sm.s2[js * 32 + g * 8 + jj];

            short8 pfr[4];
            #pragma unroll
            for (int mt = 0; mt < 4; ++mt) {
                union { unsigned int u[4]; short8 s; } pk;
                #pragma unroll
                for (int q2 = 0; q2 < 4; ++q2) {
                    float e0 = lrelu(s1v[mt] + s2l[2 * q2]);
                    float e1 = lrelu(s1v[mt] + s2l[2 * q2 + 1]);
                    float p0 = __builtin_amdgcn_exp2f((e0 - mv[mt]) * L2E) * lv[mt];
                    float p1 = __builtin_amdgcn_exp2f((e1 - mv[mt]) * L2E) * lv[mt];
                    pk.u[q2] = (unsigned int)f2bf(p0) | ((unsigned int)f2bf(p1) << 16);
                }
                pfr[mt] = pk.s;
            }
            #pragma unroll
            for (int nt = 0; nt < 8; ++nt) {
                int c  = ng2 * 128 + nt * 16 + li;
                int kc = js * 4 + g;
                short8 vf = *(const short8*)&sm.xb[c * 256 + ((kc ^ (c & 7)) << 3)];
                #pragma unroll
                for (int mt = 0; mt < 4; ++mt)
                    oacc[mt][nt] = __builtin_amdgcn_mfma_f32_16x16x32_bf16(
                        pfr[mt], vf, oacc[mt][nt], 0, 0, 0);
            }
        }

        // write out [b][i][c] f32 (C/D layout: col=li, row=4g+reg)
        size_t ob = (size_t)b * (256 * 256);
        #pragma unroll
        for (int mt = 0; mt < 4; ++mt)
            #pragma unroll
            for (int nt = 0; nt < 8; ++nt) {
                int c  = ng2 * 128 + nt * 16 + li;
                int i0 = ig2 * 64 + mt * 16 + 4 * g;
                #pragma unroll
                for (int q2 = 0; q2 < 4; ++q2)
                    out[ob + (size_t)(i0 + q2) * 256 + c] = oacc[mt][nt][q2];
            }
    }
}

extern "C" void kernel_launch(void* const* d_in, const int* in_sizes, int n_in,
                              void* d_out, int out_size, void* d_ws, size_t ws_size,
                              hipStream_t stream) {
    (void)in_sizes; (void)n_in; (void)d_ws; (void)ws_size; (void)out_size;
    const int*   seq   = (const int*)d_in[0];
    const float* emb   = (const float*)d_in[1];
    const float* pos   = (const float*)d_in[2];
    const float* W     = (const float*)d_in[3];
    const float* a1    = (const float*)d_in[4];
    const float* a2    = (const float*)d_in[5];
    const float* gamma = (const float*)d_in[6];
    const float* beta  = (const float*)d_in[7];
    hipLaunchKernelGGL(gat_fused, dim3(256), dim3(512), 0, stream,
                       seq, emb, pos, W, a1, a2, gamma, beta, (float*)d_out);
}